// Round 8
// baseline (370.236 us; speedup 1.0000x reference)
//
#include <hip/hip_runtime.h>
#include <math.h>

#define N_NODES 50000
#define N_EDGES 800000
#define NFEAT 256
#define HID 64
#define NCLS 40
#define EPS_RES 0.3f
#define SCAN_BLOCKS ((N_NODES + 255) / 256)  // 196
#define PROJ_BLOCKS ((N_NODES + 63) / 64)    // 782
#define DEG_BLOCKS (N_EDGES / 256)           // 3125
#define RZ 36  // LDS row pitch: K-chunk 32 + 4 pad (same 2-way banking as 68)

typedef unsigned int uint;
typedef unsigned short ushort;

__device__ __forceinline__ float bflo(uint u) { return __uint_as_float(u << 16); }
__device__ __forceinline__ float bfhi(uint u) { return __uint_as_float(u & 0xFFFF0000u); }
__device__ __forceinline__ uint bf16rne(float f) {
    uint u = __float_as_uint(f);
    return (u + 0x7FFFu + ((u >> 16) & 1u)) >> 16;
}
__device__ __forceinline__ uint bf16rne2(float a, float b) {
    return bf16rne(a) | (bf16rne(b) << 16);
}

// ================= fused degree (atomic-pipe-bound) + proj GEMM (VALU-bound) =============
// Device atomics run at a structural ~19 ops/ns with ~33B write-through each (R1/R5/R6;
// scope annotations don't change the lowering — R7). While the atomic pipe drains, the
// CUs' VALU/LDS are idle, so the independent x@W1^T projection (+ fused y/z gate
// projections) runs in sibling blocks of the same dispatch.
__global__ __launch_bounds__(256) void fused_deg_proj(
    const int* __restrict__ row, const int* __restrict__ col,
    int* __restrict__ degi, int* __restrict__ cnti, int* __restrict__ rankc,
    const float* __restrict__ x, const float* __restrict__ W1, const float* __restrict__ b1,
    const float* __restrict__ gw, float* __restrict__ ha, ushort* __restrict__ habf,
    float* __restrict__ y, float* __restrict__ z) {
    __shared__ float smem[2 * 64 * RZ];  // 18.4 KB -> 8 blocks/CU
    int b = blockIdx.x;
    int t = threadIdx.x;
    int k4 = b >> 2;
    bool isproj = ((b & 3) == 0) && (k4 < PROJ_BLOCKS);
    if (!isproj) {
        int nproj = (b + 3) >> 2;
        if (nproj > PROJ_BLOCKS) nproj = PROJ_BLOCKS;
        int e = (b - nproj) * 256 + t;
        atomicAdd(&degi[row[e]], 1);
        rankc[e] = atomicAdd(&cnti[col[e]], 1);
        return;
    }
    // ---- proj block k4: 64 nodes x 64 hid, K-chunks of 32 ----
    float* xs = smem;
    float* ws = smem + 64 * RZ;
    int nb = k4 * 64;
    int lane = t & 63, w = t >> 6;
    int l15 = lane & 15, g = lane >> 4;
    int hbase = 16 * w + 4 * g;
    float acc[4][4];
#pragma unroll
    for (int j = 0; j < 4; j++)
#pragma unroll
        for (int i = 0; i < 4; i++) acc[j][i] = 0.f;

    for (int kc = 0; kc < NFEAT; kc += 32) {
        __syncthreads();
#pragma unroll
        for (int i = 0; i < 2; i++) {
            int idx = t + 256 * i;       // 0..511
            int r_ = idx >> 3;           // row 0..63
            int kq = idx & 7;            // float4 slot 0..7
            int gn = nb + r_;
            float4 v = make_float4(0.f, 0.f, 0.f, 0.f);
            if (gn < N_NODES) v = *(const float4*)(x + (size_t)gn * NFEAT + kc + kq * 4);
            *(float4*)(xs + r_ * RZ + kq * 4) = v;
            float4 wv = *(const float4*)(W1 + (size_t)r_ * NFEAT + kc + kq * 4);
            *(float4*)(ws + r_ * RZ + kq * 4) = wv;
        }
        __syncthreads();
#pragma unroll
        for (int k = 0; k < 32; k += 4) {
            float4 a[4], bb[4];
#pragma unroll
            for (int j = 0; j < 4; j++) a[j] = *(const float4*)(xs + (l15 + 16 * j) * RZ + k);
#pragma unroll
            for (int i = 0; i < 4; i++) bb[i] = *(const float4*)(ws + (hbase + i) * RZ + k);
#pragma unroll
            for (int j = 0; j < 4; j++)
#pragma unroll
                for (int i = 0; i < 4; i++)
                    acc[j][i] += a[j].x * bb[i].x + a[j].y * bb[i].y + a[j].z * bb[i].z + a[j].w * bb[i].w;
        }
    }
    float4 bias = *(const float4*)(b1 + hbase);
    float4 wa4 = *(const float4*)(gw + hbase);
    float4 wb4 = *(const float4*)(gw + HID + hbase);
    int slot = w * 4 + g;  // 0..15
    __syncthreads();       // done reading xs/ws; reuse for y/z partials
#pragma unroll
    for (int j = 0; j < 4; j++) {
        int gn = nb + l15 + 16 * j;
        float4 o;
        o.x = fmaxf(acc[j][0] + bias.x, 0.f);
        o.y = fmaxf(acc[j][1] + bias.y, 0.f);
        o.z = fmaxf(acc[j][2] + bias.z, 0.f);
        o.w = fmaxf(acc[j][3] + bias.w, 0.f);
        if (gn < N_NODES) {
            *(float4*)(ha + (size_t)gn * HID + hbase) = o;
            uint2 pk;
            pk.x = bf16rne2(o.x, o.y);
            pk.y = bf16rne2(o.z, o.w);
            *(uint2*)(habf + (size_t)gn * HID + hbase) = pk;
        }
        xs[(l15 + 16 * j) * 16 + slot] = o.x * wa4.x + o.y * wa4.y + o.z * wa4.z + o.w * wa4.w;
        ws[(l15 + 16 * j) * 16 + slot] = o.x * wb4.x + o.y * wb4.y + o.z * wb4.z + o.w * wb4.w;
    }
    __syncthreads();
    if (t < 64 && nb + t < N_NODES) {
        float sa = 0.f, sb = 0.f;
#pragma unroll
        for (int s = 0; s < 16; s++) { sa += xs[t * 16 + s]; sb += ws[t * 16 + s]; }
        y[nb + t] = sa;
        z[nb + t] = sb;
    }
}

// ---------------- 3-phase grid-wide exclusive scan of cnti -> off (+ fused nd/invcnt) ----
__device__ __forceinline__ int block_excl_scan_256(int v, int t, int* wsum) {
    int lane = t & 63, w = t >> 6;
    int sv = v;
#pragma unroll
    for (int d = 1; d < 64; d <<= 1) {
        int o = __shfl_up(sv, d);
        if (lane >= d) sv += o;
    }
    if (lane == 63) wsum[w] = sv;
    __syncthreads();
    int add = 0;
    for (int i = 0; i < w; i++) add += wsum[i];
    return sv + add - v;
}

__global__ void scan1_kernel(const int* __restrict__ cnti, const int* __restrict__ degi,
                             int* __restrict__ off, int* __restrict__ bsum,
                             float* __restrict__ nd, float* __restrict__ invcnt) {
    __shared__ int wsum[4];
    int t = threadIdx.x;
    int idx = blockIdx.x * 256 + t;
    int v = (idx < N_NODES) ? cnti[idx] : 0;
    if (idx < N_NODES) {
        int d = degi[idx]; if (d < 1) d = 1;
        nd[idx] = rsqrtf((float)d);
        int c = v; if (c < 1) c = 1;
        invcnt[idx] = 1.0f / (float)c;
    }
    int excl = block_excl_scan_256(v, t, wsum);
    if (idx < N_NODES) off[idx] = excl;
    if (t == 255) bsum[blockIdx.x] = excl + v;
}

__global__ void scan2_kernel(int* __restrict__ bsum) {
    __shared__ int wsum[4];
    int t = threadIdx.x;
    int v = (t < SCAN_BLOCKS) ? bsum[t] : 0;
    int excl = block_excl_scan_256(v, t, wsum);
    if (t < SCAN_BLOCKS) bsum[t] = excl;
}

__global__ void scan3_kernel(int* __restrict__ off, const int* __restrict__ bsum) {
    int t = threadIdx.x;
    int idx = blockIdx.x * 256 + t;
    if (idx < N_NODES) off[idx] += bsum[blockIdx.x];
    if (idx == 0) off[N_NODES] = N_EDGES;
}

// ---------------- CSR scatter: one 8B store per edge {src, nd[r]*nd[c]} ----------------
__global__ void scatter_kernel(const int* __restrict__ row, const int* __restrict__ col,
                               const int* __restrict__ rankc, const int* __restrict__ off,
                               const float* __restrict__ nd, int2* __restrict__ sedge) {
    int e = blockIdx.x * 256 + threadIdx.x;
    int r = row[e], c = col[e];
    int p = off[c] + rankc[e];
    int2 se;
    se.x = r;
    se.y = __float_as_int(nd[r] * nd[c]);
    sedge[p] = se;
}

// ---------------- CSR aggregation core: 8 edges/iter, bf16 gathers, 2-stage pipeline ----
// Dependent chain sedge->(y,row) is split across iterations: step k issues sedge for k+2
// and y/rows for k+1 (from sedge loaded at k-1), so every load has >=1 full step to land.
__device__ __forceinline__ void agg_core8(const ushort* __restrict__ hbf,
                                          const int2* __restrict__ sedge,
                                          const float* __restrict__ y,
                                          float zc_b, int e0, int e1, int q, int c8,
                                          float acc[8], float& gs_out) {
#pragma unroll
    for (int i = 0; i < 8; i++) acc[i] = 0.f;
    float gs = 0.f;
    if (e0 < e1) {
        int eA = e0 + q;
        int ecA = (eA < e1) ? eA : e0;
        int2 seA = sedge[ecA];
        float ndeA = (eA < e1) ? __int_as_float(seA.y) : 0.f;
        int eB = e0 + 8 + q;
        int ecB = (eB < e1) ? eB : e0;
        int2 seB = sedge[ecB];
        float ndeB = (eB < e1) ? __int_as_float(seB.y) : 0.f;
        float yA = y[seA.x];
        uint4 uA = *(const uint4*)(hbf + (size_t)seA.x * HID + c8);
        for (int base = e0; base < e1; base += 8) {
            // rows + y for next step (seB loaded >=1 iter ago)
            float yB = y[seB.x];
            uint4 uB = *(const uint4*)(hbf + (size_t)seB.x * HID + c8);
            // meta for step+2
            int eC = base + 16 + q;
            int ecC = (eC < e1) ? eC : e0;
            int2 seC = sedge[ecC];
            float ndeC = (eC < e1) ? __int_as_float(seC.y) : 0.f;
            // compute current
            float gv = tanhf(yA + zc_b) * ndeA;
            acc[0] += gv * bflo(uA.x);
            acc[1] += gv * bfhi(uA.x);
            acc[2] += gv * bflo(uA.y);
            acc[3] += gv * bfhi(uA.y);
            acc[4] += gv * bflo(uA.z);
            acc[5] += gv * bfhi(uA.z);
            acc[6] += gv * bflo(uA.w);
            acc[7] += gv * bfhi(uA.w);
            gs += gv;
            yA = yB; uA = uB; ndeA = ndeB;
            seB = seC; ndeB = ndeC;
        }
    }
#pragma unroll
    for (int s = 8; s < 64; s <<= 1) {
#pragma unroll
        for (int i = 0; i < 8; i++) acc[i] += __shfl_xor(acc[i], s);
        gs += __shfl_xor(gs, s);
    }
    gs_out = gs;
}

// ---------------- layer 1 agg + fused y2/z2; writes bf16 hbbf only ----------------
__global__ void agg1_kernel(const float* __restrict__ ha, const ushort* __restrict__ habf,
                            const int2* __restrict__ sedge, const int* __restrict__ off,
                            const float* __restrict__ invcnt, const float* __restrict__ y,
                            const float* __restrict__ z, const float* __restrict__ gb,
                            const float* __restrict__ gw2, ushort* __restrict__ hbbf,
                            float* __restrict__ y2, float* __restrict__ z2) {
    int t = threadIdx.x;
    int lane = t & 63;
    int node = blockIdx.x * 4 + (t >> 6);
    int q = lane >> 3, c8 = (lane & 7) * 8;
    float4 ra = *(const float4*)(ha + (size_t)node * HID + c8);
    float4 rb = *(const float4*)(ha + (size_t)node * HID + c8 + 4);
    float raw8[8] = {ra.x, ra.y, ra.z, ra.w, rb.x, rb.y, rb.z, rb.w};
    float zc_b = z[node] + gb[0];
    float acc[8]; float gs;
    agg_core8(habf, sedge, y, zc_b, off[node], off[node + 1], q, c8, acc, gs);
    float invc = invcnt[node];
    float o[8];
#pragma unroll
    for (int i = 0; i < 8; i++) o[i] = EPS_RES * raw8[i] + (acc[i] + gs * raw8[i]) * invc;
    if (q == 0) {
        uint4 pk;
        pk.x = bf16rne2(o[0], o[1]);
        pk.y = bf16rne2(o[2], o[3]);
        pk.z = bf16rne2(o[4], o[5]);
        pk.w = bf16rne2(o[6], o[7]);
        *(uint4*)(hbbf + (size_t)node * HID + c8) = pk;
    }
    float4 wa0 = *(const float4*)(gw2 + c8);
    float4 wa1 = *(const float4*)(gw2 + c8 + 4);
    float4 wb0 = *(const float4*)(gw2 + HID + c8);
    float4 wb1 = *(const float4*)(gw2 + HID + c8 + 4);
    float p = o[0] * wa0.x + o[1] * wa0.y + o[2] * wa0.z + o[3] * wa0.w
            + o[4] * wa1.x + o[5] * wa1.y + o[6] * wa1.z + o[7] * wa1.w;
    float qq = o[0] * wb0.x + o[1] * wb0.y + o[2] * wb0.z + o[3] * wb0.w
             + o[4] * wb1.x + o[5] * wb1.y + o[6] * wb1.z + o[7] * wb1.w;
#pragma unroll
    for (int s = 1; s < 8; s <<= 1) { p += __shfl_xor(p, s); qq += __shfl_xor(qq, s); }
    if (lane == 0) { y2[node] = p; z2[node] = qq; }
}

// ---------------- layer 2 agg + classifier + log_softmax ----------------
__global__ void agg2_kernel(const ushort* __restrict__ hbbf, const float* __restrict__ ha,
                            const int2* __restrict__ sedge, const int* __restrict__ off,
                            const float* __restrict__ invcnt, const float* __restrict__ y2,
                            const float* __restrict__ z2, const float* __restrict__ gb,
                            const float* __restrict__ W2, const float* __restrict__ b2,
                            float* __restrict__ out) {
    __shared__ float w2s[NCLS * 65];
    __shared__ float b2s[NCLS];
    __shared__ float hs[4 * HID];
    int t = threadIdx.x;
    for (int i = t; i < NCLS * HID; i += 256) w2s[(i >> 6) * 65 + (i & 63)] = W2[i];
    if (t < NCLS) b2s[t] = b2[t];
    int lane = t & 63;
    int wv = t >> 6;
    int node = blockIdx.x * 4 + wv;
    int q = lane >> 3, c8 = (lane & 7) * 8;
    uint4 hc = *(const uint4*)(hbbf + (size_t)node * HID + c8);
    float hcv[8] = {bflo(hc.x), bfhi(hc.x), bflo(hc.y), bfhi(hc.y),
                    bflo(hc.z), bfhi(hc.z), bflo(hc.w), bfhi(hc.w)};
    float4 ra = *(const float4*)(ha + (size_t)node * HID + c8);
    float4 rb = *(const float4*)(ha + (size_t)node * HID + c8 + 4);
    float raw8[8] = {ra.x, ra.y, ra.z, ra.w, rb.x, rb.y, rb.z, rb.w};
    float zc_b = z2[node] + gb[0];
    float acc[8]; float gs;
    agg_core8(hbbf, sedge, y2, zc_b, off[node], off[node + 1], q, c8, acc, gs);
    float invc = invcnt[node];
    if (q == 0) {
        float4 o0, o1;
        o0.x = EPS_RES * raw8[0] + (acc[0] + gs * hcv[0]) * invc;
        o0.y = EPS_RES * raw8[1] + (acc[1] + gs * hcv[1]) * invc;
        o0.z = EPS_RES * raw8[2] + (acc[2] + gs * hcv[2]) * invc;
        o0.w = EPS_RES * raw8[3] + (acc[3] + gs * hcv[3]) * invc;
        o1.x = EPS_RES * raw8[4] + (acc[4] + gs * hcv[4]) * invc;
        o1.y = EPS_RES * raw8[5] + (acc[5] + gs * hcv[5]) * invc;
        o1.z = EPS_RES * raw8[6] + (acc[6] + gs * hcv[6]) * invc;
        o1.w = EPS_RES * raw8[7] + (acc[7] + gs * hcv[7]) * invc;
        *(float4*)(hs + wv * HID + c8) = o0;
        *(float4*)(hs + wv * HID + c8 + 4) = o1;
    }
    __syncthreads();
    float logit = 0.f;
    if (lane < NCLS) {
        const float* wr = w2s + lane * 65;
        const float* hrow = hs + wv * HID;
#pragma unroll
        for (int k = 0; k < HID; k++) logit += hrow[k] * wr[k];
        logit += b2s[lane];
    }
    float v = (lane < NCLS) ? logit : -INFINITY;
#pragma unroll
    for (int s = 1; s < 64; s <<= 1) v = fmaxf(v, __shfl_xor(v, s));
    float ex = (lane < NCLS) ? expf(logit - v) : 0.f;
#pragma unroll
    for (int s = 1; s < 64; s <<= 1) ex += __shfl_xor(ex, s);
    float ls = v + logf(ex);
    if (lane < NCLS) out[node * NCLS + lane] = logit - ls;
}

extern "C" void kernel_launch(void* const* d_in, const int* in_sizes, int n_in,
                              void* d_out, int out_size, void* d_ws, size_t ws_size,
                              hipStream_t stream) {
    const float* x  = (const float*)d_in[0];
    const int*   ei = (const int*)d_in[1];
    const float* W1 = (const float*)d_in[2];
    const float* b1 = (const float*)d_in[3];
    const float* W2 = (const float*)d_in[4];
    const float* b2 = (const float*)d_in[5];
    const float* gw = (const float*)d_in[6];
    const float* gb = (const float*)d_in[7];
    float* out = (float*)d_out;

    // ws layout (4B words): [degi N][cnti N][rankc E][sedge 2E][nd N][invcnt N]
    //   [y N][z N][y2 N][z2 N][ha 64N][habf 32N][hbbf 32N][off N+1][bsum 196]
    // rankc is standalone now (degree & proj run concurrently in one dispatch).
    // total ~= 9.25M words = 37.0 MB (< proven-safe 39.4 MB from R1)
    int*   degi   = (int*)d_ws;
    int*   cnti   = degi + N_NODES;
    int*   rankc  = cnti + N_NODES;
    int2*  sedge  = (int2*)(rankc + N_EDGES);
    float* nd     = (float*)(sedge + N_EDGES);
    float* invcnt = nd + N_NODES;
    float* y      = invcnt + N_NODES;
    float* z      = y + N_NODES;
    float* y2     = z + N_NODES;
    float* z2     = y2 + N_NODES;
    float* ha     = z2 + N_NODES;
    ushort* habf  = (ushort*)(ha + (size_t)N_NODES * HID);
    ushort* hbbf  = habf + (size_t)N_NODES * HID;
    int*   off    = (int*)(hbbf + (size_t)N_NODES * HID);
    int*   bsum   = off + N_NODES + 1;

    const int* row = ei;
    const int* col = ei + N_EDGES;

    hipMemsetAsync(degi, 0, (size_t)2 * N_NODES * sizeof(int), stream);

    fused_deg_proj<<<PROJ_BLOCKS + DEG_BLOCKS, 256, 0, stream>>>(
        row, col, degi, cnti, rankc, x, W1, b1, gw, ha, habf, y, z);
    scan1_kernel<<<SCAN_BLOCKS, 256, 0, stream>>>(cnti, degi, off, bsum, nd, invcnt);
    scan2_kernel<<<1, 256, 0, stream>>>(bsum);
    scan3_kernel<<<SCAN_BLOCKS, 256, 0, stream>>>(off, bsum);
    scatter_kernel<<<N_EDGES / 256, 256, 0, stream>>>(row, col, rankc, off, nd, sedge);

    agg1_kernel<<<N_NODES / 4, 256, 0, stream>>>(ha, habf, sedge, off, invcnt, y, z, gb,
                                                 gw + 2 * HID, hbbf, y2, z2);
    agg2_kernel<<<N_NODES / 4, 256, 0, stream>>>(hbbf, ha, sedge, off, invcnt, y2, z2,
                                                 gb + 1, W2, b2, out);
}

// Round 9
// 316.975 us; speedup vs baseline: 1.1680x; 1.1680x over previous
//
#include <hip/hip_runtime.h>
#include <math.h>

#define N_NODES 50000
#define N_EDGES 800000
#define NFEAT 256
#define HID 64
#define NCLS 40
#define EPS_RES 0.3f
#define ROWSZ 68  // LDS row pitch for proj (64 + 4 pad)
#define SCAN_BLOCKS ((N_NODES + 255) / 256)  // 196

typedef unsigned int uint;
typedef unsigned short ushort;

__device__ __forceinline__ float bflo(uint u) { return __uint_as_float(u << 16); }
__device__ __forceinline__ float bfhi(uint u) { return __uint_as_float(u & 0xFFFF0000u); }
__device__ __forceinline__ uint bf16rne(float f) {
    uint u = __float_as_uint(f);
    return (u + 0x7FFFu + ((u >> 16) & 1u)) >> 16;
}
__device__ __forceinline__ uint bf16rne2(float a, float b) {
    return bf16rne(a) | (bf16rne(b) << 16);
}

// ---------------- degree + per-edge rank ----------------
// Structural floor: 2 device atomics/edge at ~19 ops/ns, ~33B write-through each
// (R1/R5/R6). Scope tricks (R7) and co-scheduled compute (R8) both fail: atomics
// write through regardless of scope, and the storm poisons latency for co-resident
// memory traffic. Leave this kernel alone.
__global__ void degree_kernel(const int* __restrict__ row, const int* __restrict__ col,
                              int* __restrict__ degi, int* __restrict__ cnti,
                              int* __restrict__ rankc) {
    int e = blockIdx.x * 256 + threadIdx.x;
    atomicAdd(&degi[row[e]], 1);
    rankc[e] = atomicAdd(&cnti[col[e]], 1);
}

// ---------------- 3-phase grid-wide exclusive scan of cnti -> off (+ fused nd/invcnt) ----
__device__ __forceinline__ int block_excl_scan_256(int v, int t, int* wsum) {
    int lane = t & 63, w = t >> 6;
    int sv = v;
#pragma unroll
    for (int d = 1; d < 64; d <<= 1) {
        int o = __shfl_up(sv, d);
        if (lane >= d) sv += o;
    }
    if (lane == 63) wsum[w] = sv;
    __syncthreads();
    int add = 0;
    for (int i = 0; i < w; i++) add += wsum[i];
    return sv + add - v;
}

__global__ void scan1_kernel(const int* __restrict__ cnti, const int* __restrict__ degi,
                             int* __restrict__ off, int* __restrict__ bsum,
                             float* __restrict__ nd, float* __restrict__ invcnt) {
    __shared__ int wsum[4];
    int t = threadIdx.x;
    int idx = blockIdx.x * 256 + t;
    int v = (idx < N_NODES) ? cnti[idx] : 0;
    if (idx < N_NODES) {
        int d = degi[idx]; if (d < 1) d = 1;
        nd[idx] = rsqrtf((float)d);
        int c = v; if (c < 1) c = 1;
        invcnt[idx] = 1.0f / (float)c;
    }
    int excl = block_excl_scan_256(v, t, wsum);
    if (idx < N_NODES) off[idx] = excl;
    if (t == 255) bsum[blockIdx.x] = excl + v;
}

__global__ void scan2_kernel(int* __restrict__ bsum) {
    __shared__ int wsum[4];
    int t = threadIdx.x;
    int v = (t < SCAN_BLOCKS) ? bsum[t] : 0;
    int excl = block_excl_scan_256(v, t, wsum);
    if (t < SCAN_BLOCKS) bsum[t] = excl;
}

__global__ void scan3_kernel(int* __restrict__ off, const int* __restrict__ bsum) {
    int t = threadIdx.x;
    int idx = blockIdx.x * 256 + t;
    if (idx < N_NODES) off[idx] += bsum[blockIdx.x];
    if (idx == 0) off[N_NODES] = N_EDGES;
}

// ---------------- CSR scatter: one 8B store per edge {src, nd[r]*nd[c]} ----------------
__global__ void scatter_kernel(const int* __restrict__ row, const int* __restrict__ col,
                               const int* __restrict__ rankc, const int* __restrict__ off,
                               const float* __restrict__ nd, int2* __restrict__ sedge) {
    int e = blockIdx.x * 256 + threadIdx.x;
    int r = row[e], c = col[e];
    int p = off[c] + rankc[e];
    int2 se;
    se.x = r;
    se.y = __float_as_int(nd[r] * nd[c]);
    sedge[p] = se;
}

// ---------------- input projection + fused y/z gate projections ----------------
// ha(fp32) + habf(bf16) = relu(x @ W1^T + b1);  y = ha.wa, z = ha.wb (layer-1 gate).
__global__ __launch_bounds__(256) void proj_kernel(const float* __restrict__ x,
                                                   const float* __restrict__ W1,
                                                   const float* __restrict__ b1,
                                                   const float* __restrict__ gw,
                                                   float* __restrict__ ha,
                                                   ushort* __restrict__ habf,
                                                   float* __restrict__ y,
                                                   float* __restrict__ z) {
    __shared__ float xs[64 * ROWSZ];
    __shared__ float ws[64 * ROWSZ];
    int t = threadIdx.x;
    int nb = blockIdx.x * 64;
    int lane = t & 63, w = t >> 6;
    int l15 = lane & 15, g = lane >> 4;
    int hbase = 16 * w + 4 * g;
    float acc[4][4];
#pragma unroll
    for (int j = 0; j < 4; j++)
#pragma unroll
        for (int i = 0; i < 4; i++) acc[j][i] = 0.f;

    for (int kc = 0; kc < NFEAT; kc += 64) {
        __syncthreads();
#pragma unroll
        for (int i = 0; i < 4; i++) {
            int idx = t + 256 * i;
            int r_ = idx >> 4;
            int kq = idx & 15;
            int gn = nb + r_;
            float4 v = make_float4(0.f, 0.f, 0.f, 0.f);
            if (gn < N_NODES) v = *(const float4*)(x + (size_t)gn * NFEAT + kc + kq * 4);
            *(float4*)(xs + r_ * ROWSZ + kq * 4) = v;
            float4 wv = *(const float4*)(W1 + (size_t)r_ * NFEAT + kc + kq * 4);
            *(float4*)(ws + r_ * ROWSZ + kq * 4) = wv;
        }
        __syncthreads();
#pragma unroll 4
        for (int k = 0; k < 64; k += 4) {
            float4 a[4], b[4];
#pragma unroll
            for (int j = 0; j < 4; j++) a[j] = *(const float4*)(xs + (l15 + 16 * j) * ROWSZ + k);
#pragma unroll
            for (int i = 0; i < 4; i++) b[i] = *(const float4*)(ws + (hbase + i) * ROWSZ + k);
#pragma unroll
            for (int j = 0; j < 4; j++)
#pragma unroll
                for (int i = 0; i < 4; i++)
                    acc[j][i] += a[j].x * b[i].x + a[j].y * b[i].y + a[j].z * b[i].z + a[j].w * b[i].w;
        }
    }
    float4 bias = *(const float4*)(b1 + hbase);
    float4 wa4 = *(const float4*)(gw + hbase);
    float4 wb4 = *(const float4*)(gw + HID + hbase);
    int slot = w * 4 + g;  // 0..15
    __syncthreads();       // done with xs/ws tiles; reuse as y/z partial scratch
#pragma unroll
    for (int j = 0; j < 4; j++) {
        int gn = nb + l15 + 16 * j;
        float4 o;
        o.x = fmaxf(acc[j][0] + bias.x, 0.f);
        o.y = fmaxf(acc[j][1] + bias.y, 0.f);
        o.z = fmaxf(acc[j][2] + bias.z, 0.f);
        o.w = fmaxf(acc[j][3] + bias.w, 0.f);
        if (gn < N_NODES) {
            *(float4*)(ha + (size_t)gn * HID + hbase) = o;
            uint2 pk;
            pk.x = bf16rne2(o.x, o.y);
            pk.y = bf16rne2(o.z, o.w);
            *(uint2*)(habf + (size_t)gn * HID + hbase) = pk;
        }
        xs[(l15 + 16 * j) * 16 + slot] = o.x * wa4.x + o.y * wa4.y + o.z * wa4.z + o.w * wa4.w;
        ws[(l15 + 16 * j) * 16 + slot] = o.x * wb4.x + o.y * wb4.y + o.z * wb4.z + o.w * wb4.w;
    }
    __syncthreads();
    if (t < 64 && nb + t < N_NODES) {
        float sa = 0.f, sb = 0.f;
#pragma unroll
        for (int s = 0; s < 16; s++) { sa += xs[t * 16 + s]; sb += ws[t * 16 + s]; }
        y[nb + t] = sa;
        z[nb + t] = sb;
    }
}

// ---------------- CSR aggregation core: 8 edges/iter, bf16 gathers, 2-stage pipeline ----
// Dependent chain sedge->(y,row) split across iterations: step k issues sedge for k+2
// and y/rows for k+1, so every gather has >=1 full iteration to land. (Verified R8.)
__device__ __forceinline__ void agg_core8(const ushort* __restrict__ hbf,
                                          const int2* __restrict__ sedge,
                                          const float* __restrict__ y,
                                          float zc_b, int e0, int e1, int q, int c8,
                                          float acc[8], float& gs_out) {
#pragma unroll
    for (int i = 0; i < 8; i++) acc[i] = 0.f;
    float gs = 0.f;
    if (e0 < e1) {
        int eA = e0 + q;
        int ecA = (eA < e1) ? eA : e0;
        int2 seA = sedge[ecA];
        float ndeA = (eA < e1) ? __int_as_float(seA.y) : 0.f;
        int eB = e0 + 8 + q;
        int ecB = (eB < e1) ? eB : e0;
        int2 seB = sedge[ecB];
        float ndeB = (eB < e1) ? __int_as_float(seB.y) : 0.f;
        float yA = y[seA.x];
        uint4 uA = *(const uint4*)(hbf + (size_t)seA.x * HID + c8);
        for (int base = e0; base < e1; base += 8) {
            float yB = y[seB.x];
            uint4 uB = *(const uint4*)(hbf + (size_t)seB.x * HID + c8);
            int eC = base + 16 + q;
            int ecC = (eC < e1) ? eC : e0;
            int2 seC = sedge[ecC];
            float ndeC = (eC < e1) ? __int_as_float(seC.y) : 0.f;
            float gv = tanhf(yA + zc_b) * ndeA;
            acc[0] += gv * bflo(uA.x);
            acc[1] += gv * bfhi(uA.x);
            acc[2] += gv * bflo(uA.y);
            acc[3] += gv * bfhi(uA.y);
            acc[4] += gv * bflo(uA.z);
            acc[5] += gv * bfhi(uA.z);
            acc[6] += gv * bflo(uA.w);
            acc[7] += gv * bfhi(uA.w);
            gs += gv;
            yA = yB; uA = uB; ndeA = ndeB;
            seB = seC; ndeB = ndeC;
        }
    }
#pragma unroll
    for (int s = 8; s < 64; s <<= 1) {
#pragma unroll
        for (int i = 0; i < 8; i++) acc[i] += __shfl_xor(acc[i], s);
        gs += __shfl_xor(gs, s);
    }
    gs_out = gs;
}

// ---------------- layer 1 agg + fused y2/z2; writes bf16 hbbf only ----------------
__global__ void agg1_kernel(const float* __restrict__ ha, const ushort* __restrict__ habf,
                            const int2* __restrict__ sedge, const int* __restrict__ off,
                            const float* __restrict__ invcnt, const float* __restrict__ y,
                            const float* __restrict__ z, const float* __restrict__ gb,
                            const float* __restrict__ gw2, ushort* __restrict__ hbbf,
                            float* __restrict__ y2, float* __restrict__ z2) {
    int t = threadIdx.x;
    int lane = t & 63;
    int node = blockIdx.x * 4 + (t >> 6);
    int q = lane >> 3, c8 = (lane & 7) * 8;
    float4 ra = *(const float4*)(ha + (size_t)node * HID + c8);
    float4 rb = *(const float4*)(ha + (size_t)node * HID + c8 + 4);
    float raw8[8] = {ra.x, ra.y, ra.z, ra.w, rb.x, rb.y, rb.z, rb.w};
    float zc_b = z[node] + gb[0];
    float acc[8]; float gs;
    agg_core8(habf, sedge, y, zc_b, off[node], off[node + 1], q, c8, acc, gs);
    float invc = invcnt[node];
    float o[8];
#pragma unroll
    for (int i = 0; i < 8; i++) o[i] = EPS_RES * raw8[i] + (acc[i] + gs * raw8[i]) * invc;
    if (q == 0) {
        uint4 pk;
        pk.x = bf16rne2(o[0], o[1]);
        pk.y = bf16rne2(o[2], o[3]);
        pk.z = bf16rne2(o[4], o[5]);
        pk.w = bf16rne2(o[6], o[7]);
        *(uint4*)(hbbf + (size_t)node * HID + c8) = pk;
    }
    float4 wa0 = *(const float4*)(gw2 + c8);
    float4 wa1 = *(const float4*)(gw2 + c8 + 4);
    float4 wb0 = *(const float4*)(gw2 + HID + c8);
    float4 wb1 = *(const float4*)(gw2 + HID + c8 + 4);
    float p = o[0] * wa0.x + o[1] * wa0.y + o[2] * wa0.z + o[3] * wa0.w
            + o[4] * wa1.x + o[5] * wa1.y + o[6] * wa1.z + o[7] * wa1.w;
    float qq = o[0] * wb0.x + o[1] * wb0.y + o[2] * wb0.z + o[3] * wb0.w
             + o[4] * wb1.x + o[5] * wb1.y + o[6] * wb1.z + o[7] * wb1.w;
#pragma unroll
    for (int s = 1; s < 8; s <<= 1) { p += __shfl_xor(p, s); qq += __shfl_xor(qq, s); }
    if (lane == 0) { y2[node] = p; z2[node] = qq; }
}

// ---------------- layer 2 agg + classifier + log_softmax ----------------
__global__ void agg2_kernel(const ushort* __restrict__ hbbf, const float* __restrict__ ha,
                            const int2* __restrict__ sedge, const int* __restrict__ off,
                            const float* __restrict__ invcnt, const float* __restrict__ y2,
                            const float* __restrict__ z2, const float* __restrict__ gb,
                            const float* __restrict__ W2, const float* __restrict__ b2,
                            float* __restrict__ out) {
    __shared__ float w2s[NCLS * 65];
    __shared__ float b2s[NCLS];
    __shared__ float hs[4 * HID];
    int t = threadIdx.x;
    for (int i = t; i < NCLS * HID; i += 256) w2s[(i >> 6) * 65 + (i & 63)] = W2[i];
    if (t < NCLS) b2s[t] = b2[t];
    int lane = t & 63;
    int wv = t >> 6;
    int node = blockIdx.x * 4 + wv;
    int q = lane >> 3, c8 = (lane & 7) * 8;
    uint4 hc = *(const uint4*)(hbbf + (size_t)node * HID + c8);
    float hcv[8] = {bflo(hc.x), bfhi(hc.x), bflo(hc.y), bfhi(hc.y),
                    bflo(hc.z), bfhi(hc.z), bflo(hc.w), bfhi(hc.w)};
    float4 ra = *(const float4*)(ha + (size_t)node * HID + c8);
    float4 rb = *(const float4*)(ha + (size_t)node * HID + c8 + 4);
    float raw8[8] = {ra.x, ra.y, ra.z, ra.w, rb.x, rb.y, rb.z, rb.w};
    float zc_b = z2[node] + gb[0];
    float acc[8]; float gs;
    agg_core8(hbbf, sedge, y2, zc_b, off[node], off[node + 1], q, c8, acc, gs);
    float invc = invcnt[node];
    if (q == 0) {
        float4 o0, o1;
        o0.x = EPS_RES * raw8[0] + (acc[0] + gs * hcv[0]) * invc;
        o0.y = EPS_RES * raw8[1] + (acc[1] + gs * hcv[1]) * invc;
        o0.z = EPS_RES * raw8[2] + (acc[2] + gs * hcv[2]) * invc;
        o0.w = EPS_RES * raw8[3] + (acc[3] + gs * hcv[3]) * invc;
        o1.x = EPS_RES * raw8[4] + (acc[4] + gs * hcv[4]) * invc;
        o1.y = EPS_RES * raw8[5] + (acc[5] + gs * hcv[5]) * invc;
        o1.z = EPS_RES * raw8[6] + (acc[6] + gs * hcv[6]) * invc;
        o1.w = EPS_RES * raw8[7] + (acc[7] + gs * hcv[7]) * invc;
        *(float4*)(hs + wv * HID + c8) = o0;
        *(float4*)(hs + wv * HID + c8 + 4) = o1;
    }
    __syncthreads();
    float logit = 0.f;
    if (lane < NCLS) {
        const float* wr = w2s + lane * 65;
        const float* hrow = hs + wv * HID;
#pragma unroll
        for (int k = 0; k < HID; k++) logit += hrow[k] * wr[k];
        logit += b2s[lane];
    }
    float v = (lane < NCLS) ? logit : -INFINITY;
#pragma unroll
    for (int s = 1; s < 64; s <<= 1) v = fmaxf(v, __shfl_xor(v, s));
    float ex = (lane < NCLS) ? expf(logit - v) : 0.f;
#pragma unroll
    for (int s = 1; s < 64; s <<= 1) ex += __shfl_xor(ex, s);
    float ls = v + logf(ex);
    if (lane < NCLS) out[node * NCLS + lane] = logit - ls;
}

extern "C" void kernel_launch(void* const* d_in, const int* in_sizes, int n_in,
                              void* d_out, int out_size, void* d_ws, size_t ws_size,
                              hipStream_t stream) {
    const float* x  = (const float*)d_in[0];
    const int*   ei = (const int*)d_in[1];
    const float* W1 = (const float*)d_in[2];
    const float* b1 = (const float*)d_in[3];
    const float* W2 = (const float*)d_in[4];
    const float* b2 = (const float*)d_in[5];
    const float* gw = (const float*)d_in[6];
    const float* gb = (const float*)d_in[7];
    float* out = (float*)d_out;

    // ws layout (4B words): [degi N][cnti N][sedge 2E][nd N][invcnt N][y N][z N][y2 N][z2 N]
    //   [ha 64N][habf 32N][hbbf 32N][off N+1][bsum 196]
    // rankc aliases habf (written by degree, consumed by scatter, dead before proj writes
    // habf — launch order guarantees this). total ~= 8.45M words = 33.8 MB
    int*   degi   = (int*)d_ws;
    int*   cnti   = degi + N_NODES;
    int2*  sedge  = (int2*)(cnti + N_NODES);
    float* nd     = (float*)(sedge + N_EDGES);
    float* invcnt = nd + N_NODES;
    float* y      = invcnt + N_NODES;
    float* z      = y + N_NODES;
    float* y2     = z + N_NODES;
    float* z2     = y2 + N_NODES;
    float* ha     = z2 + N_NODES;
    ushort* habf  = (ushort*)(ha + (size_t)N_NODES * HID);
    ushort* hbbf  = habf + (size_t)N_NODES * HID;
    int*   off    = (int*)(hbbf + (size_t)N_NODES * HID);
    int*   bsum   = off + N_NODES + 1;
    int*   rankc  = (int*)habf;  // E ints <= 32N words, dead before proj writes habf

    const int* row = ei;
    const int* col = ei + N_EDGES;

    hipMemsetAsync(degi, 0, (size_t)2 * N_NODES * sizeof(int), stream);

    degree_kernel<<<N_EDGES / 256, 256, 0, stream>>>(row, col, degi, cnti, rankc);
    scan1_kernel<<<SCAN_BLOCKS, 256, 0, stream>>>(cnti, degi, off, bsum, nd, invcnt);
    scan2_kernel<<<1, 256, 0, stream>>>(bsum);
    scan3_kernel<<<SCAN_BLOCKS, 256, 0, stream>>>(off, bsum);
    scatter_kernel<<<N_EDGES / 256, 256, 0, stream>>>(row, col, rankc, off, nd, sedge);
    proj_kernel<<<(N_NODES + 63) / 64, 256, 0, stream>>>(x, W1, b1, gw, ha, habf, y, z);

    agg1_kernel<<<N_NODES / 4, 256, 0, stream>>>(ha, habf, sedge, off, invcnt, y, z, gb,
                                                 gw + 2 * HID, hbbf, y2, z2);
    agg2_kernel<<<N_NODES / 4, 256, 0, stream>>>(hbbf, ha, sedge, off, invcnt, y2, z2,
                                                 gb + 1, W2, b2, out);
}

// Round 10
// 268.139 us; speedup vs baseline: 1.3808x; 1.1821x over previous
//
#include <hip/hip_runtime.h>
#include <math.h>

#define N_NODES 50000
#define N_EDGES 800000
#define NFEAT 256
#define HID 64
#define NCLS 40
#define EPS_RES 0.3f
#define ROWSZ 68  // LDS row pitch for proj (64 + 4 pad)
#define SCAN_BLOCKS ((N_NODES + 255) / 256)  // 196
#define EB 32                 // edge chunks
#define CHUNK (N_EDGES / EB)  // 25000
#define NR 4                  // node ranges
#define RNG (N_NODES / NR)    // 12500 -> 50KB LDS histogram

typedef unsigned int uint;
typedef unsigned short ushort;

__device__ __forceinline__ float bflo(uint u) { return __uint_as_float(u << 16); }
__device__ __forceinline__ float bfhi(uint u) { return __uint_as_float(u & 0xFFFF0000u); }
__device__ __forceinline__ uint bf16rne(float f) {
    uint u = __float_as_uint(f);
    return (u + 0x7FFFu + ((u >> 16) & 1u)) >> 16;
}
__device__ __forceinline__ uint bf16rne2(float a, float b) {
    return bf16rne(a) | (bf16rne(b) << 16);
}

// ---------------- degree histograms via LDS binning: ZERO global atomics ----------------
// Global atomics cost ~33B write-through at a structural ~19 ops/ns (R1/R5/R6; scope
// R7 and overlap R8 both failed). Instead: 256 blocks = 32 edge-chunks x 4 node-ranges
// x 2 sides; each block keeps a private 50KB LDS histogram of its range, streams its
// chunk coalesced, atomics stay in LDS. Side 1 (col) also records the LDS-atomic return
// as the per-(chunk,col) local rank. Histograms land in degM/cntM[chunk][node].
__global__ __launch_bounds__(256) void hist_kernel(const int* __restrict__ row,
                                                   const int* __restrict__ col,
                                                   int* __restrict__ degM,
                                                   int* __restrict__ cntM,
                                                   int* __restrict__ rank_local) {
    __shared__ int hist[RNG];
    int t = threadIdx.x;
    int chunk = blockIdx.x;
    int lo = blockIdx.y * RNG;
    int side = blockIdx.z;
    for (int j = t; j < RNG; j += 256) hist[j] = 0;
    __syncthreads();
    const int* idx = side ? col : row;
    int e0 = chunk * CHUNK;
    if (side == 0) {
        for (int base = 0; base < CHUNK; base += 1024) {
            int vb[4];
#pragma unroll
            for (int j = 0; j < 4; j++) {
                int i = base + j * 256 + t;
                vb[j] = (i < CHUNK) ? idx[e0 + i] : -1;
            }
#pragma unroll
            for (int j = 0; j < 4; j++) {
                uint v = (uint)(vb[j] - lo);
                if (v < RNG) atomicAdd(&hist[v], 1);
            }
        }
    } else {
        for (int base = 0; base < CHUNK; base += 1024) {
            int vb[4], ib[4];
#pragma unroll
            for (int j = 0; j < 4; j++) {
                int i = base + j * 256 + t;
                ib[j] = i;
                vb[j] = (i < CHUNK) ? idx[e0 + i] : -1;
            }
#pragma unroll
            for (int j = 0; j < 4; j++) {
                uint v = (uint)(vb[j] - lo);
                if (v < RNG) rank_local[e0 + ib[j]] = atomicAdd(&hist[v], 1);
            }
        }
    }
    __syncthreads();
    int* M = side ? cntM : degM;
    for (int j = t; j < RNG; j += 256) M[chunk * N_NODES + lo + j] = hist[j];
}

// ---------------- scan1: chunk-reduce (nd/invcnt + in-place cntM bases) + block scan ----
__device__ __forceinline__ int block_excl_scan_256(int v, int t, int* wsum) {
    int lane = t & 63, w = t >> 6;
    int sv = v;
#pragma unroll
    for (int d = 1; d < 64; d <<= 1) {
        int o = __shfl_up(sv, d);
        if (lane >= d) sv += o;
    }
    if (lane == 63) wsum[w] = sv;
    __syncthreads();
    int add = 0;
    for (int i = 0; i < w; i++) add += wsum[i];
    return sv + add - v;
}

__global__ void scan1_kernel(const int* __restrict__ degM, int* __restrict__ cntM,
                             int* __restrict__ off, int* __restrict__ bsum,
                             float* __restrict__ nd, float* __restrict__ invcnt) {
    __shared__ int wsum[4];
    int t = threadIdx.x;
    int idx = blockIdx.x * 256 + t;
    int v = 0;
    if (idx < N_NODES) {
        int sD = 0;
#pragma unroll
        for (int c = 0; c < EB; c++) sD += degM[c * N_NODES + idx];
        int run = 0;
#pragma unroll
        for (int c = 0; c < EB; c++) {
            int cv = cntM[c * N_NODES + idx];
            cntM[c * N_NODES + idx] = run;  // exclusive base for this chunk within bucket
            run += cv;
        }
        v = run;
        if (sD < 1) sD = 1;
        nd[idx] = rsqrtf((float)sD);
        int cc = run; if (cc < 1) cc = 1;
        invcnt[idx] = 1.0f / (float)cc;
    }
    int excl = block_excl_scan_256(v, t, wsum);
    if (idx < N_NODES) off[idx] = excl;
    if (t == 255) bsum[blockIdx.x] = excl + v;
}

__global__ void scan2_kernel(int* __restrict__ bsum) {
    __shared__ int wsum[4];
    int t = threadIdx.x;
    int v = (t < SCAN_BLOCKS) ? bsum[t] : 0;
    int excl = block_excl_scan_256(v, t, wsum);
    if (t < SCAN_BLOCKS) bsum[t] = excl;
}

__global__ void scan3_kernel(int* __restrict__ off, const int* __restrict__ bsum) {
    int t = threadIdx.x;
    int idx = blockIdx.x * 256 + t;
    if (idx < N_NODES) off[idx] += bsum[blockIdx.x];
    if (idx == 0) off[N_NODES] = N_EDGES;
}

// ---------------- CSR scatter: atomic-free, one 8B store per edge ----------------
__global__ void scatter_kernel(const int* __restrict__ row, const int* __restrict__ col,
                               const int* __restrict__ rank_local, const int* __restrict__ cntM,
                               const int* __restrict__ off, const float* __restrict__ nd,
                               int2* __restrict__ sedge) {
    int e = blockIdx.x * 256 + threadIdx.x;
    int r = row[e], c = col[e];
    int ch = e / CHUNK;
    int p = off[c] + cntM[ch * N_NODES + c] + rank_local[e];
    int2 se;
    se.x = r;
    se.y = __float_as_int(nd[r] * nd[c]);
    sedge[p] = se;
}

// ---------------- input projection + fused y/z gate projections ----------------
__global__ __launch_bounds__(256) void proj_kernel(const float* __restrict__ x,
                                                   const float* __restrict__ W1,
                                                   const float* __restrict__ b1,
                                                   const float* __restrict__ gw,
                                                   float* __restrict__ ha,
                                                   ushort* __restrict__ habf,
                                                   float* __restrict__ y,
                                                   float* __restrict__ z) {
    __shared__ float xs[64 * ROWSZ];
    __shared__ float ws[64 * ROWSZ];
    int t = threadIdx.x;
    int nb = blockIdx.x * 64;
    int lane = t & 63, w = t >> 6;
    int l15 = lane & 15, g = lane >> 4;
    int hbase = 16 * w + 4 * g;
    float acc[4][4];
#pragma unroll
    for (int j = 0; j < 4; j++)
#pragma unroll
        for (int i = 0; i < 4; i++) acc[j][i] = 0.f;

    for (int kc = 0; kc < NFEAT; kc += 64) {
        __syncthreads();
#pragma unroll
        for (int i = 0; i < 4; i++) {
            int idx = t + 256 * i;
            int r_ = idx >> 4;
            int kq = idx & 15;
            int gn = nb + r_;
            float4 v = make_float4(0.f, 0.f, 0.f, 0.f);
            if (gn < N_NODES) v = *(const float4*)(x + (size_t)gn * NFEAT + kc + kq * 4);
            *(float4*)(xs + r_ * ROWSZ + kq * 4) = v;
            float4 wv = *(const float4*)(W1 + (size_t)r_ * NFEAT + kc + kq * 4);
            *(float4*)(ws + r_ * ROWSZ + kq * 4) = wv;
        }
        __syncthreads();
#pragma unroll 4
        for (int k = 0; k < 64; k += 4) {
            float4 a[4], b[4];
#pragma unroll
            for (int j = 0; j < 4; j++) a[j] = *(const float4*)(xs + (l15 + 16 * j) * ROWSZ + k);
#pragma unroll
            for (int i = 0; i < 4; i++) b[i] = *(const float4*)(ws + (hbase + i) * ROWSZ + k);
#pragma unroll
            for (int j = 0; j < 4; j++)
#pragma unroll
                for (int i = 0; i < 4; i++)
                    acc[j][i] += a[j].x * b[i].x + a[j].y * b[i].y + a[j].z * b[i].z + a[j].w * b[i].w;
        }
    }
    float4 bias = *(const float4*)(b1 + hbase);
    float4 wa4 = *(const float4*)(gw + hbase);
    float4 wb4 = *(const float4*)(gw + HID + hbase);
    int slot = w * 4 + g;  // 0..15
    __syncthreads();       // done with xs/ws tiles; reuse as y/z partial scratch
#pragma unroll
    for (int j = 0; j < 4; j++) {
        int gn = nb + l15 + 16 * j;
        float4 o;
        o.x = fmaxf(acc[j][0] + bias.x, 0.f);
        o.y = fmaxf(acc[j][1] + bias.y, 0.f);
        o.z = fmaxf(acc[j][2] + bias.z, 0.f);
        o.w = fmaxf(acc[j][3] + bias.w, 0.f);
        if (gn < N_NODES) {
            *(float4*)(ha + (size_t)gn * HID + hbase) = o;
            uint2 pk;
            pk.x = bf16rne2(o.x, o.y);
            pk.y = bf16rne2(o.z, o.w);
            *(uint2*)(habf + (size_t)gn * HID + hbase) = pk;
        }
        xs[(l15 + 16 * j) * 16 + slot] = o.x * wa4.x + o.y * wa4.y + o.z * wa4.z + o.w * wa4.w;
        ws[(l15 + 16 * j) * 16 + slot] = o.x * wb4.x + o.y * wb4.y + o.z * wb4.z + o.w * wb4.w;
    }
    __syncthreads();
    if (t < 64 && nb + t < N_NODES) {
        float sa = 0.f, sb = 0.f;
#pragma unroll
        for (int s = 0; s < 16; s++) { sa += xs[t * 16 + s]; sb += ws[t * 16 + s]; }
        y[nb + t] = sa;
        z[nb + t] = sb;
    }
}

// ---------------- CSR aggregation core: 8 edges/iter, bf16 gathers, 2-stage pipeline ----
__device__ __forceinline__ void agg_core8(const ushort* __restrict__ hbf,
                                          const int2* __restrict__ sedge,
                                          const float* __restrict__ y,
                                          float zc_b, int e0, int e1, int q, int c8,
                                          float acc[8], float& gs_out) {
#pragma unroll
    for (int i = 0; i < 8; i++) acc[i] = 0.f;
    float gs = 0.f;
    if (e0 < e1) {
        int eA = e0 + q;
        int ecA = (eA < e1) ? eA : e0;
        int2 seA = sedge[ecA];
        float ndeA = (eA < e1) ? __int_as_float(seA.y) : 0.f;
        int eB = e0 + 8 + q;
        int ecB = (eB < e1) ? eB : e0;
        int2 seB = sedge[ecB];
        float ndeB = (eB < e1) ? __int_as_float(seB.y) : 0.f;
        float yA = y[seA.x];
        uint4 uA = *(const uint4*)(hbf + (size_t)seA.x * HID + c8);
        for (int base = e0; base < e1; base += 8) {
            float yB = y[seB.x];
            uint4 uB = *(const uint4*)(hbf + (size_t)seB.x * HID + c8);
            int eC = base + 16 + q;
            int ecC = (eC < e1) ? eC : e0;
            int2 seC = sedge[ecC];
            float ndeC = (eC < e1) ? __int_as_float(seC.y) : 0.f;
            float gv = tanhf(yA + zc_b) * ndeA;
            acc[0] += gv * bflo(uA.x);
            acc[1] += gv * bfhi(uA.x);
            acc[2] += gv * bflo(uA.y);
            acc[3] += gv * bfhi(uA.y);
            acc[4] += gv * bflo(uA.z);
            acc[5] += gv * bfhi(uA.z);
            acc[6] += gv * bflo(uA.w);
            acc[7] += gv * bfhi(uA.w);
            gs += gv;
            yA = yB; uA = uB; ndeA = ndeB;
            seB = seC; ndeB = ndeC;
        }
    }
#pragma unroll
    for (int s = 8; s < 64; s <<= 1) {
#pragma unroll
        for (int i = 0; i < 8; i++) acc[i] += __shfl_xor(acc[i], s);
        gs += __shfl_xor(gs, s);
    }
    gs_out = gs;
}

// ---------------- layer 1 agg + fused y2/z2; writes bf16 hbbf only ----------------
__global__ void agg1_kernel(const float* __restrict__ ha, const ushort* __restrict__ habf,
                            const int2* __restrict__ sedge, const int* __restrict__ off,
                            const float* __restrict__ invcnt, const float* __restrict__ y,
                            const float* __restrict__ z, const float* __restrict__ gb,
                            const float* __restrict__ gw2, ushort* __restrict__ hbbf,
                            float* __restrict__ y2, float* __restrict__ z2) {
    int t = threadIdx.x;
    int lane = t & 63;
    int node = blockIdx.x * 4 + (t >> 6);
    int q = lane >> 3, c8 = (lane & 7) * 8;
    float4 ra = *(const float4*)(ha + (size_t)node * HID + c8);
    float4 rb = *(const float4*)(ha + (size_t)node * HID + c8 + 4);
    float raw8[8] = {ra.x, ra.y, ra.z, ra.w, rb.x, rb.y, rb.z, rb.w};
    float zc_b = z[node] + gb[0];
    float acc[8]; float gs;
    agg_core8(habf, sedge, y, zc_b, off[node], off[node + 1], q, c8, acc, gs);
    float invc = invcnt[node];
    float o[8];
#pragma unroll
    for (int i = 0; i < 8; i++) o[i] = EPS_RES * raw8[i] + (acc[i] + gs * raw8[i]) * invc;
    if (q == 0) {
        uint4 pk;
        pk.x = bf16rne2(o[0], o[1]);
        pk.y = bf16rne2(o[2], o[3]);
        pk.z = bf16rne2(o[4], o[5]);
        pk.w = bf16rne2(o[6], o[7]);
        *(uint4*)(hbbf + (size_t)node * HID + c8) = pk;
    }
    float4 wa0 = *(const float4*)(gw2 + c8);
    float4 wa1 = *(const float4*)(gw2 + c8 + 4);
    float4 wb0 = *(const float4*)(gw2 + HID + c8);
    float4 wb1 = *(const float4*)(gw2 + HID + c8 + 4);
    float p = o[0] * wa0.x + o[1] * wa0.y + o[2] * wa0.z + o[3] * wa0.w
            + o[4] * wa1.x + o[5] * wa1.y + o[6] * wa1.z + o[7] * wa1.w;
    float qq = o[0] * wb0.x + o[1] * wb0.y + o[2] * wb0.z + o[3] * wb0.w
             + o[4] * wb1.x + o[5] * wb1.y + o[6] * wb1.z + o[7] * wb1.w;
#pragma unroll
    for (int s = 1; s < 8; s <<= 1) { p += __shfl_xor(p, s); qq += __shfl_xor(qq, s); }
    if (lane == 0) { y2[node] = p; z2[node] = qq; }
}

// ---------------- layer 2 agg + classifier + log_softmax ----------------
__global__ void agg2_kernel(const ushort* __restrict__ hbbf, const float* __restrict__ ha,
                            const int2* __restrict__ sedge, const int* __restrict__ off,
                            const float* __restrict__ invcnt, const float* __restrict__ y2,
                            const float* __restrict__ z2, const float* __restrict__ gb,
                            const float* __restrict__ W2, const float* __restrict__ b2,
                            float* __restrict__ out) {
    __shared__ float w2s[NCLS * 65];
    __shared__ float b2s[NCLS];
    __shared__ float hs[4 * HID];
    int t = threadIdx.x;
    for (int i = t; i < NCLS * HID; i += 256) w2s[(i >> 6) * 65 + (i & 63)] = W2[i];
    if (t < NCLS) b2s[t] = b2[t];
    int lane = t & 63;
    int wv = t >> 6;
    int node = blockIdx.x * 4 + wv;
    int q = lane >> 3, c8 = (lane & 7) * 8;
    uint4 hc = *(const uint4*)(hbbf + (size_t)node * HID + c8);
    float hcv[8] = {bflo(hc.x), bfhi(hc.x), bflo(hc.y), bfhi(hc.y),
                    bflo(hc.z), bfhi(hc.z), bflo(hc.w), bfhi(hc.w)};
    float4 ra = *(const float4*)(ha + (size_t)node * HID + c8);
    float4 rb = *(const float4*)(ha + (size_t)node * HID + c8 + 4);
    float raw8[8] = {ra.x, ra.y, ra.z, ra.w, rb.x, rb.y, rb.z, rb.w};
    float zc_b = z2[node] + gb[0];
    float acc[8]; float gs;
    agg_core8(hbbf, sedge, y2, zc_b, off[node], off[node + 1], q, c8, acc, gs);
    float invc = invcnt[node];
    if (q == 0) {
        float4 o0, o1;
        o0.x = EPS_RES * raw8[0] + (acc[0] + gs * hcv[0]) * invc;
        o0.y = EPS_RES * raw8[1] + (acc[1] + gs * hcv[1]) * invc;
        o0.z = EPS_RES * raw8[2] + (acc[2] + gs * hcv[2]) * invc;
        o0.w = EPS_RES * raw8[3] + (acc[3] + gs * hcv[3]) * invc;
        o1.x = EPS_RES * raw8[4] + (acc[4] + gs * hcv[4]) * invc;
        o1.y = EPS_RES * raw8[5] + (acc[5] + gs * hcv[5]) * invc;
        o1.z = EPS_RES * raw8[6] + (acc[6] + gs * hcv[6]) * invc;
        o1.w = EPS_RES * raw8[7] + (acc[7] + gs * hcv[7]) * invc;
        *(float4*)(hs + wv * HID + c8) = o0;
        *(float4*)(hs + wv * HID + c8 + 4) = o1;
    }
    __syncthreads();
    float logit = 0.f;
    if (lane < NCLS) {
        const float* wr = w2s + lane * 65;
        const float* hrow = hs + wv * HID;
#pragma unroll
        for (int k = 0; k < HID; k++) logit += hrow[k] * wr[k];
        logit += b2s[lane];
    }
    float v = (lane < NCLS) ? logit : -INFINITY;
#pragma unroll
    for (int s = 1; s < 64; s <<= 1) v = fmaxf(v, __shfl_xor(v, s));
    float ex = (lane < NCLS) ? expf(logit - v) : 0.f;
#pragma unroll
    for (int s = 1; s < 64; s <<= 1) ex += __shfl_xor(ex, s);
    float ls = v + logf(ex);
    if (lane < NCLS) out[node * NCLS + lane] = logit - ls;
}

extern "C" void kernel_launch(void* const* d_in, const int* in_sizes, int n_in,
                              void* d_out, int out_size, void* d_ws, size_t ws_size,
                              hipStream_t stream) {
    const float* x  = (const float*)d_in[0];
    const int*   ei = (const int*)d_in[1];
    const float* W1 = (const float*)d_in[2];
    const float* b1 = (const float*)d_in[3];
    const float* W2 = (const float*)d_in[4];
    const float* b2 = (const float*)d_in[5];
    const float* gw = (const float*)d_in[6];
    const float* gb = (const float*)d_in[7];
    float* out = (float*)d_out;

    // ws layout (4B words): [sedge 2E][nd N][invcnt N][y N][z N][y2 N][z2 N]
    //   [ha 64N][habf 32N][hbbf 32N][off N+1][bsum 196]
    // degM/cntM (EB*N each = 12.8MB total) alias ha; rank_local (E) aliases habf.
    // All consumed by scatter before proj writes ha/habf (launch order). ~33.7 MB.
    int2*  sedge  = (int2*)d_ws;
    float* nd     = (float*)(sedge + N_EDGES);
    float* invcnt = nd + N_NODES;
    float* y      = invcnt + N_NODES;
    float* z      = y + N_NODES;
    float* y2     = z + N_NODES;
    float* z2     = y2 + N_NODES;
    float* ha     = z2 + N_NODES;
    ushort* habf  = (ushort*)(ha + (size_t)N_NODES * HID);
    ushort* hbbf  = habf + (size_t)N_NODES * HID;
    int*   off    = (int*)(hbbf + (size_t)N_NODES * HID);
    int*   bsum   = off + N_NODES + 1;
    int*   degM   = (int*)ha;                  // EB*N ints
    int*   cntM   = degM + (size_t)EB * N_NODES;  // EB*N ints (both inside ha's 64N)
    int*   rank_local = (int*)habf;            // E ints <= 32N words

    const int* row = ei;
    const int* col = ei + N_EDGES;

    hist_kernel<<<dim3(EB, NR, 2), 256, 0, stream>>>(row, col, degM, cntM, rank_local);
    scan1_kernel<<<SCAN_BLOCKS, 256, 0, stream>>>(degM, cntM, off, bsum, nd, invcnt);
    scan2_kernel<<<1, 256, 0, stream>>>(bsum);
    scan3_kernel<<<SCAN_BLOCKS, 256, 0, stream>>>(off, bsum);
    scatter_kernel<<<N_EDGES / 256, 256, 0, stream>>>(row, col, rank_local, cntM, off, nd, sedge);
    proj_kernel<<<(N_NODES + 63) / 64, 256, 0, stream>>>(x, W1, b1, gw, ha, habf, y, z);

    agg1_kernel<<<N_NODES / 4, 256, 0, stream>>>(ha, habf, sedge, off, invcnt, y, z, gb,
                                                 gw + 2 * HID, hbbf, y2, z2);
    agg2_kernel<<<N_NODES / 4, 256, 0, stream>>>(hbbf, ha, sedge, off, invcnt, y2, z2,
                                                 gb + 1, W2, b2, out);
}